// Round 18
// baseline (222.477 us; speedup 1.0000x reference)
//
#include <hip/hip_runtime.h>

// BootstrapEnsemble: M=100 MLPs (16 -> 128 -> 4x(128x128) -> {mu, log sigma}),
// shared batch N=16384.
//  1) cvt_weights: one-shot fp32->bf16 of x/W1/Wh/Wmu/Wsig into d_ws. Wh is
//     PRE-SWIZZLED (8-elem group j of row r at col 8*(j ^ (r&15))): staged
//     linearly via global_load_lds, read back conflict-free (0 bank conflicts
//     measured since R12).
//  2) ens_mlp: register-resident-h MLP. Block = 4 waves x 64-row band
//     (256 thr, LB(256,2)), LDS = 64 KB W double-buffer -> 2 independent
//     blocks/CU. R18: force the MFMA accumulator into ARCH VGPRs:
//       - empty inline-asm "+v" pin on each acc tile before build_hfrag
//         (the v-constraint makes regalloc keep the chain in VGPRs; R17's
//         VGPR_Count=120 means acc was in AGPRs -> every build read paid a
//         v_accvgpr_read, ~1280 hidden VALU ops/wave/block = the measured
//         VALU gap);
//       - bias loaded DIRECTLY into acc (both nt banks, VMEM-only init) so
//         every MFMA is uniform in-place accumulate (no C copies/movs).
//     B-frag rebuild: cvt_pk -> packed relu (v_pk_max_i16) -> permlane32_swap.
//     Hidden layers: mfma_f32_32x32x16_bf16 intrinsic (hazard handling stays
//     with the compiler).

typedef float  f32x4  __attribute__((ext_vector_type(4)));
typedef float  f32x16 __attribute__((ext_vector_type(16)));
typedef __bf16 bf16x4 __attribute__((ext_vector_type(4)));
typedef __bf16 bf16x8 __attribute__((ext_vector_type(8)));
typedef short  s16x4  __attribute__((ext_vector_type(4)));

union BF4  { bf16x4 v; uint2 u2; };
union FRAG { bf16x8 v; uint4 u4; };
union PKW  { uint2 u2; s16x4 s4; };

#define MODELS 100
#define NPT    16384
#define HDIM   128
#define SG_OFF (MODELS * NPT)

// d_ws layout (bf16 element offsets)
#define XB_OFF   0                       // x:    16384 x 16 (linear)
#define W1B_OFF  262144                  // W1:   100 x 128 x 16 (linear)
#define WHB_OFF  466944                  // Wh:   100 x 4 x 128 x 128 (SWIZZLED)
#define WMU_OFF  7020544                 // Wmu:  100 x 128 (linear)
#define WSG_OFF  7033344                 // Wsig: 100 x 128 (linear)

#define GTOT 880768                      // total 8-elem groups

__global__ __launch_bounds__(256) void cvt_weights(
    const float* __restrict__ x,   const float* __restrict__ W1,
    const float* __restrict__ Wh,  const float* __restrict__ Wmu,
    const float* __restrict__ Wsg, unsigned short* __restrict__ ws)
{
  int gid = blockIdx.x * 256 + threadIdx.x;
  if (gid >= GTOT) return;
  const float* src;
  unsigned int dst;
  if (gid < 32768) {
    src = x + gid * 8;                       dst = XB_OFF + gid * 8;
  } else if (gid < 58368) {
    int g = gid - 32768;
    src = W1 + g * 8;                        dst = W1B_OFF + g * 8;
  } else if (gid < 877568) {
    int g = gid - 58368;
    int chunk  = g >> 11;                    // m*4 + layer
    int within = g & 2047;
    int r   = within >> 4;                   // k_out row
    int col = ((within & 15) * 8) ^ ((r & 15) << 3);  // full-depth swizzle
    src = Wh + (size_t)g * 8;
    dst = WHB_OFF + chunk * 16384 + r * HDIM + col;
  } else if (gid < 879168) {
    int g = gid - 877568;
    src = Wmu + g * 8;                       dst = WMU_OFF + g * 8;
  } else {
    int g = gid - 879168;
    src = Wsg + g * 8;                       dst = WSG_OFF + g * 8;
  }
  f32x4 a = *(const f32x4*)src;
  f32x4 b = *(const f32x4*)(src + 4);
  BF4 lo, hi;
  lo.v = __builtin_convertvector(a, bf16x4);
  hi.v = __builtin_convertvector(b, bf16x4);
  uint4 u; u.x = lo.u2.x; u.y = lo.u2.y; u.z = hi.u2.x; u.w = hi.u2.y;
  *(uint4*)&ws[dst] = u;
}

__device__ __forceinline__ void gload_lds16(const void* g, void* l) {
  __builtin_amdgcn_global_load_lds(
      (const __attribute__((address_space(1))) void*)g,
      (__attribute__((address_space(3))) void*)l, 16, 0, 0);
}

#define MFMA32(A,B,C) __builtin_amdgcn_mfma_f32_32x32x16_bf16((A),(B),(C),0,0,0)

// D (f32x16, per lane: col n = l31, row k' = 32*kt2 + 8*(reg>>2) + 4*hi + (reg&3))
// -> next-layer B-frags (lane holds h[n=l31][k = 16*ks + 8*hi + 0..7]).
// cvt_pk to bf16 pairs, PACKED relu (v_pk_max_i16), then permlane32_swap.
__device__ __forceinline__ void build_hfrag(const f32x16 (&acc)[2][4],
                                            uint4 (&hf)[2][8]) {
  const s16x4 z4 = {0, 0, 0, 0};
  #pragma unroll
  for (int nt = 0; nt < 2; ++nt) {
    #pragma unroll
    for (int kt2 = 0; kt2 < 4; ++kt2) {
      uint2 P[4];
      #pragma unroll
      for (int q = 0; q < 4; ++q) {
        f32x4 v;
        v[0] = acc[nt][kt2][4*q+0]; v[1] = acc[nt][kt2][4*q+1];
        v[2] = acc[nt][kt2][4*q+2]; v[3] = acc[nt][kt2][4*q+3];
        BF4 b; b.v = __builtin_convertvector(v, bf16x4);
        PKW p; p.u2 = b.u2;
        p.s4 = __builtin_elementwise_max(p.s4, z4);   // packed relu
        P[q] = p.u2;
      }
      #pragma unroll
      for (int sb = 0; sb < 2; ++sb) {
        unsigned int x0 = P[2*sb].x, y0 = P[2*sb+1].x;
        unsigned int x1 = P[2*sb].y, y1 = P[2*sb+1].y;
        asm("v_permlane32_swap_b32 %0, %1" : "+v"(x0), "+v"(y0));
        asm("v_permlane32_swap_b32 %0, %1" : "+v"(x1), "+v"(y1));
        uint4 f; f.x = x0; f.y = x1; f.z = y0; f.w = y1;
        hf[nt][2*kt2+sb] = f;
      }
    }
  }
}

// Force the acc tiles into arch VGPRs (empty asm with a v-constraint).
__device__ __forceinline__ void pin_vgpr(f32x16 (&acc)[2][4]) {
  #pragma unroll
  for (int nt = 0; nt < 2; ++nt)
    #pragma unroll
    for (int kt2 = 0; kt2 < 4; ++kt2)
      asm("" : "+v"(acc[nt][kt2]));
}

__global__ __launch_bounds__(256, 2) void ens_mlp(
    const unsigned short* __restrict__ ws,
    const float* __restrict__ b1,  const float* __restrict__ bh,
    const float* __restrict__ bmu, const float* __restrict__ bsg,
    float* __restrict__ out)
{
  __shared__ unsigned short wlds[2][HDIM * HDIM];   // 64 KB: W double-buffer

  // XCD-chunked bijective swizzle: 6400 blocks = 8 XCDs * 800
  const int bid = blockIdx.x;
  const int swz = (bid & 7) * 800 + (bid >> 3);
  const int m   = swz >> 6;            // model 0..99
  const int nb0 = (swz & 63) << 8;     // 256-row chunk base

  const int t    = threadIdx.x;
  const int lane = t & 63;
  const int wv   = t >> 6;             // wave 0..3
  const int l31  = lane & 31;
  const int hi   = lane >> 5;
  const int nbw  = nb0 + wv * 64;      // this wave's private 64-row band

  const unsigned short* whm = ws + WHB_OFF + m * 65536;

  // ---- prologue: stage hidden layers 0 and 1 into the two buffers --------
  #pragma unroll
  for (int b = 0; b < 2; ++b) {
    const char* src = (const char*)(whm + b * 16384);
    char* dst = (char*)wlds[b];
    #pragma unroll
    for (int it = 0; it < 8; ++it) {
      int off = t * 16 + it * 4096;
      gload_lds16(src + off, dst + off);
    }
  }

  uint4  hfrag[2][8];   // h B-frags: [nt][ks], lane holds h[n][16ks+8hi+0..7]
  f32x16 acc[2][4];     // [nt][kt2] -- pinned to arch VGPRs

  // ---- layer 1: K=16, exact (no padding); bias direct into acc -----------
  {
    const unsigned short* W1m = ws + W1B_OFF + m * (HDIM * 16);
    const unsigned short* xp  = ws + XB_OFF;
    FRAG w1f[4], xf[2];
    #pragma unroll
    for (int kt2 = 0; kt2 < 4; ++kt2)
      w1f[kt2].v = *(const bf16x8*)&W1m[(kt2 * 32 + l31) * 16 + hi * 8];
    #pragma unroll
    for (int nt = 0; nt < 2; ++nt)
      xf[nt].v = *(const bf16x8*)&xp[(nbw + nt * 32 + l31) * 16 + hi * 8];
    #pragma unroll
    for (int nt = 0; nt < 2; ++nt)
      #pragma unroll
      for (int kt2 = 0; kt2 < 4; ++kt2) {
        union { f32x16 v; f32x4 q[4]; } A;
        #pragma unroll
        for (int q = 0; q < 4; ++q)
          A.q[q] = *(const f32x4*)(b1 + m * HDIM + kt2 * 32 + q * 8 + hi * 4);
        acc[nt][kt2] = MFMA32(w1f[kt2].v, xf[nt].v, A.v);
      }
  }
  pin_vgpr(acc);
  build_hfrag(acc, hfrag);

  __syncthreads();   // vmcnt(0) drain: layers 0 & 1 staged and visible

  // ---- 4 hidden layers: W double-buffered, h register-resident -----------
  #pragma unroll
  for (int i = 0; i < 4; ++i) {
    const char* wl = (const char*)wlds[i & 1];
    const float* bp = bh + m * 512 + i * HDIM;

    // bias direct into acc (VMEM-only init; both nt banks load it)
    #pragma unroll
    for (int nt = 0; nt < 2; ++nt)
      #pragma unroll
      for (int kt2 = 0; kt2 < 4; ++kt2) {
        union { f32x16 v; f32x4 q[4]; } A;
        #pragma unroll
        for (int q = 0; q < 4; ++q)
          A.q[q] = *(const f32x4*)(bp + kt2 * 32 + q * 8 + hi * 4);
        acc[nt][kt2] = A.v;
      }

    #pragma unroll
    for (int ks = 0; ks < 8; ++ks) {
      FRAG wf[4];
      #pragma unroll
      for (int kt2 = 0; kt2 < 4; ++kt2) {
        int off = (kt2 * 32 + l31) * 256 + ((ks * 32 + hi * 16) ^ ((l31 & 15) << 4));
        wf[kt2].u4 = *(const uint4*)(wl + off);
      }
      #pragma unroll
      for (int kt2 = 0; kt2 < 4; ++kt2)
        #pragma unroll
        for (int nt = 0; nt < 2; ++nt) {
          FRAG hv; hv.u4 = hfrag[nt][ks];
          acc[nt][kt2] = MFMA32(wf[kt2].v, hv.v, acc[nt][kt2]);
        }
    }
    pin_vgpr(acc);
    build_hfrag(acc, hfrag);

    // barrier FIRST (all waves done reading buf[i&1]; vmcnt(0) drains the
    // DMA issued at end of iter i-1), THEN stage layer i+2 into buf[i&1].
    if (i < 3) __syncthreads();
    if (i < 2) {
      const char* src = (const char*)(whm + (i + 2) * 16384);
      char* dst = (char*)wlds[i & 1];
      #pragma unroll
      for (int it = 0; it < 8; ++it) {
        int off = t * 16 + it * 4096;
        gload_lds16(src + off, dst + off);
      }
    }
  }

  // ---- heads: mu (k'=0) and log-sigma (k'=1) ------------------------------
  {
    FRAG hw[8];
    const unsigned short* wp = ws + (l31 == 0 ? WMU_OFF : WSG_OFF) + m * HDIM;
    #pragma unroll
    for (int ks = 0; ks < 8; ++ks) {
      if (l31 < 2) {
        hw[ks].v = *(const bf16x8*)&wp[ks * 16 + hi * 8];
      } else {
        uint4 z; z.x = 0u; z.y = 0u; z.z = 0u; z.w = 0u;
        hw[ks].u4 = z;
      }
    }
    f32x16 C;
    #pragma unroll
    for (int j = 0; j < 16; ++j) C[j] = 0.0f;
    if (hi == 0) { C[0] = bmu[m]; C[1] = bsg[m]; }

    #pragma unroll
    for (int nt = 0; nt < 2; ++nt) {
      f32x16 a2;
      #pragma unroll
      for (int ks = 0; ks < 8; ++ks) {
        FRAG hv; hv.u4 = hfrag[nt][ks];
        a2 = MFMA32(hw[ks].v, hv.v, ks == 0 ? C : a2);
      }
      if (hi == 0) {
        int n = nbw + nt * 32 + l31;
        out[m * NPT + n]          = a2[0];
        out[SG_OFF + m * NPT + n] = expf(a2[1]);
      }
    }
  }
}

extern "C" void kernel_launch(void* const* d_in, const int* in_sizes, int n_in,
                              void* d_out, int out_size, void* d_ws, size_t ws_size,
                              hipStream_t stream) {
  const float* x   = (const float*)d_in[0];
  const float* W1  = (const float*)d_in[1];
  const float* b1  = (const float*)d_in[2];
  const float* Wh  = (const float*)d_in[3];
  const float* bh  = (const float*)d_in[4];
  const float* Wmu = (const float*)d_in[5];
  const float* bmu = (const float*)d_in[6];
  const float* Wsg = (const float*)d_in[7];
  const float* bsg = (const float*)d_in[8];
  unsigned short* ws = (unsigned short*)d_ws;
  (void)in_sizes; (void)n_in; (void)out_size; (void)ws_size;

  cvt_weights<<<(GTOT + 255) / 256, 256, 0, stream>>>(x, W1, Wh, Wmu, Wsg, ws);
  ens_mlp<<<6400, 256, 0, stream>>>(ws, b1, bh, bmu, bsg, (float*)d_out);
}